// Round 5
// baseline (344.899 us; speedup 1.0000x reference)
//
#include <hip/hip_runtime.h>
#include <hip/hip_cooperative_groups.h>

namespace cg = cooperative_groups;

#define NN 100000
#define NE 3200000
#define CC 256
#define NEG_SLOPE 0.2f

// Fused exp+segsum phase: 80 edge slices x 3 node-partition passes = 240
// blocks (1 per CU; 160 KB LDS forces 1 block/CU anyway, 240 <= 256 so the
// cooperative-launch residency check passes).
#define FS_S 80
#define FS_P 3
#define FS_PART 40000        // f32 acc = 160000 B LDS (<= 163840 limit)
#define FS_ESL (NE / FS_S)   // 40000 edges per slice
#define NBLK 240
#define BLK 1024

typedef __attribute__((ext_vector_type(8))) _Float16 half8;

// ONE cooperative kernel, 4 phases separated by grid.sync(). Phases are
// identical algorithms to the round-4 separate kernels; the fusion removes
// 3 launches + inter-kernel drain bubbles and guarantees this dispatch
// surfaces in the rocprof top-5 with full counters.
__global__ __launch_bounds__(BLK) void mega_kernel(
    const float* __restrict__ x,
    const float* __restrict__ att,
    const int* __restrict__ row,
    const int* __restrict__ col,
    float* __restrict__ s_src,
    float* __restrict__ s_dst,
    _Float16* __restrict__ e_buf,
    float* __restrict__ partial /* [FS_S][NN] */,
    float* __restrict__ denom,
    float4* __restrict__ out4) {
  __shared__ float acc[FS_PART];  // 160000 B
  cg::grid_group grid = cg::this_grid();
  const int tid = threadIdx.x;
  const int bid = blockIdx.x;

  // ---- Phase A: node scores (dual dot product, 16 lanes per node). ----
  // att rows hoisted to registers (8 float4); x read once, coalesced
  // 64 B/lane -> HBM-bound ~17 us of this kernel's time.
  {
    int gl = tid & 15;
    const float4* a0 = (const float4*)att + gl * 4;         // att[:C]
    const float4* a1 = (const float4*)(att + CC) + gl * 4;  // att[C:]
    float4 av0 = a0[0], av1 = a0[1], av2 = a0[2], av3 = a0[3];
    float4 bv0 = a1[0], bv1 = a1[1], bv2 = a1[2], bv3 = a1[3];
    for (int node = bid * (BLK / 16) + (tid >> 4); node < NN;
         node += NBLK * (BLK / 16)) {
      const float4* xr = (const float4*)(x + (size_t)node * CC) + gl * 4;
      float4 x0 = xr[0], x1 = xr[1], x2 = xr[2], x3 = xr[3];
      float s0 = x0.x * av0.x + x0.y * av0.y + x0.z * av0.z + x0.w * av0.w
               + x1.x * av1.x + x1.y * av1.y + x1.z * av1.z + x1.w * av1.w
               + x2.x * av2.x + x2.y * av2.y + x2.z * av2.z + x2.w * av2.w
               + x3.x * av3.x + x3.y * av3.y + x3.z * av3.z + x3.w * av3.w;
      float s1 = x0.x * bv0.x + x0.y * bv0.y + x0.z * bv0.z + x0.w * bv0.w
               + x1.x * bv1.x + x1.y * bv1.y + x1.z * bv1.z + x1.w * bv1.w
               + x2.x * bv2.x + x2.y * bv2.y + x2.z * bv2.z + x2.w * bv2.w
               + x3.x * bv3.x + x3.y * bv3.y + x3.z * bv3.z + x3.w * bv3.w;
#pragma unroll
      for (int m = 8; m >= 1; m >>= 1) {
        s0 += __shfl_xor(s0, m, 64);  // masks <16 stay within 16-lane group
        s1 += __shfl_xor(s1, m, 64);
      }
      if (gl == 0) {
        s_src[node] = s0;
        s_dst[node] = s1;
      }
    }
  }
  grid.sync();

  // ---- Phase B: fused exp + segment-sum, 3 partition passes per slice. ----
  // Block bid -> (s = bid % 80, p = bid / 80); bid == s (mod 8) so the 3
  // sibling blocks of a slice share an XCD and run concurrently -> passes
  // 2,3 of the idx stream hit that XCD's L2. Predicated col load + s_src/
  // s_dst gathers (400 KB tables, L2-resident). Max-subtraction cancels
  // algebraically -> no segment-max pass. exp(alpha) in [e^-2, e^8]: f16
  // rel err 5e-4, safe vs 1.55e-2 threshold.
  {
    int s  = bid % FS_S;
    int p  = bid / FS_S;
    int lo = p * FS_PART;
    for (int i = tid; i < FS_PART; i += BLK) acc[i] = 0.0f;
    __syncthreads();
    const int4* row4 = (const int4*)(row + s * FS_ESL);
    const int*  cols = col + s * FS_ESL;
    _Float16* eo = e_buf + (size_t)s * FS_ESL;
    const int n8 = FS_ESL / 8;  // 5000

#define FS_SLOT(r, j)                                      \
  do {                                                     \
    int rr = (r)-lo;                                       \
    if ((unsigned)rr < FS_PART) {                          \
      float a = s_src[(r)] + s_dst[cols[8 * i + (j)]];     \
      a = (a > 0.0f) ? a : NEG_SLOPE * a;                  \
      _Float16 h = (_Float16)__expf(a);                    \
      eo[8 * i + (j)] = h;                                 \
      atomicAdd(&acc[rr], (float)h);                       \
    }                                                      \
  } while (0)

    for (int i = tid; i < n8; i += BLK) {
      int4 ra = row4[2 * i], rb = row4[2 * i + 1];
      FS_SLOT(ra.x, 0);
      FS_SLOT(ra.y, 1);
      FS_SLOT(ra.z, 2);
      FS_SLOT(ra.w, 3);
      FS_SLOT(rb.x, 4);
      FS_SLOT(rb.y, 5);
      FS_SLOT(rb.z, 6);
      FS_SLOT(rb.w, 7);
    }
#undef FS_SLOT
    __syncthreads();
    int cnt = NN - lo;
    if (cnt > FS_PART) cnt = FS_PART;
    float* outp = partial + (size_t)s * NN + lo;
    for (int i = tid; i < cnt; i += BLK) outp[i] = acc[i];
  }
  grid.sync();

  // ---- Phase C: fold 80 slice-partials, store reciprocal (32 MB read). ----
  for (int n4 = bid * BLK + tid; n4 < NN / 4; n4 += NBLK * BLK) {
    float4 sum = make_float4(0.f, 0.f, 0.f, 0.f);
#pragma unroll 8
    for (int s = 0; s < FS_S; ++s) {
      float4 v = ((const float4*)(partial + (size_t)s * NN))[n4];
      sum.x += v.x; sum.y += v.y; sum.z += v.z; sum.w += v.w;
    }
    ((float4*)denom)[n4] =
        make_float4(1.f / sum.x, 1.f / sum.y, 1.f / sum.z, 1.f / sum.w);
  }
  grid.sync();

  // ---- Phase D: normalize, 8 edges/thread, direct denom gather. ----
  {
    const int4* row4 = (const int4*)row;
    const half8* e8  = (const half8*)e_buf;
    for (int i = bid * BLK + tid; i < NE / 8; i += NBLK * BLK) {
      int4 ra = row4[2 * i], rb = row4[2 * i + 1];
      half8 ev = e8[i];
      float4 oa, ob;
      oa.x = (float)ev[0] * denom[ra.x];
      oa.y = (float)ev[1] * denom[ra.y];
      oa.z = (float)ev[2] * denom[ra.z];
      oa.w = (float)ev[3] * denom[ra.w];
      ob.x = (float)ev[4] * denom[rb.x];
      ob.y = (float)ev[5] * denom[rb.y];
      ob.z = (float)ev[6] * denom[rb.z];
      ob.w = (float)ev[7] * denom[rb.w];
      out4[2 * i]     = oa;
      out4[2 * i + 1] = ob;
    }
  }
}

extern "C" void kernel_launch(void* const* d_in, const int* in_sizes, int n_in,
                              void* d_out, int out_size, void* d_ws, size_t ws_size,
                              hipStream_t stream) {
  const float* x   = (const float*)d_in[0];
  const float* att = (const float*)d_in[1];
  const int* ei    = (const int*)d_in[2];  // (2, E): row then col (int32)
  const int* row   = ei;
  const int* col   = ei + NE;
  float4* out4     = (float4*)d_out;  // E floats, final output

  float* s_src    = (float*)d_ws;            // N f32
  float* s_dst    = s_src + NN;              // N f32
  float* denom    = s_dst + NN;              // N f32
  _Float16* e_buf = (_Float16*)(denom + NN); // E f16 (6.4 MB)
  float* partial  = (float*)(e_buf + NE);    // FS_S * N f32 (32 MB)

  void* args[] = {(void*)&x,      (void*)&att,    (void*)&row,
                  (void*)&col,    (void*)&s_src,  (void*)&s_dst,
                  (void*)&e_buf,  (void*)&partial,(void*)&denom,
                  (void*)&out4};
  hipLaunchCooperativeKernel((void*)mega_kernel, dim3(NBLK), dim3(BLK),
                             args, 0, stream);
}

// Round 6
// 252.628 us; speedup vs baseline: 1.3652x; 1.3652x over previous
//
#include <hip/hip_runtime.h>

#define NN 100000
#define NE 3200000
#define CC 256
#define NEG_SLOPE 0.2f

// Fused exp+segsum: 80 edge slices x 3 node-partition passes = 240 blocks
// (1 per CU; 160 KB LDS forces 1 block/CU anyway).
#define FS_S 80
#define FS_P 3
#define FS_PART 40000        // f32 acc = 160000 B LDS (<= 163840 limit)
#define FS_ESL (NE / FS_S)   // 40000 edges per slice
#define BLK 1024

typedef __attribute__((ext_vector_type(8))) unsigned short ushort8;

// round-to-nearest f32 -> bf16 bits
__device__ __forceinline__ unsigned short f32_to_bf16(float f) {
  union { float f; unsigned int u; } v; v.f = f;
  unsigned int b = v.u + 0x7FFFu + ((v.u >> 16) & 1u);
  return (unsigned short)(b >> 16);
}
__device__ __forceinline__ float bf16_to_f32(unsigned short h) {
  union { unsigned int u; float f; } v; v.u = ((unsigned int)h) << 16;
  return v.f;
}

// Kernel A: dual dot product, 16 lanes per node (4 nodes/wave).
// Lane gl loads x[node][16gl .. 16gl+15] (4 consecutive float4 = 64 B/lane).
// Reads x (102.4 MB) once, fully coalesced -> ~17 us at HBM floor.
__global__ __launch_bounds__(256) void node_scores_kernel(
    const float* __restrict__ x,
    const float* __restrict__ att,
    float* __restrict__ s_src,
    float* __restrict__ s_dst) {
  int t    = blockIdx.x * blockDim.x + threadIdx.x;
  int node = t >> 4;
  int gl   = t & 15;
  if (node >= NN) return;
  const float4* xr = (const float4*)(x + (size_t)node * CC) + gl * 4;
  const float4* a0 = (const float4*)att + gl * 4;         // att[:C]
  const float4* a1 = (const float4*)(att + CC) + gl * 4;  // att[C:]
  float s0 = 0.f, s1 = 0.f;
#pragma unroll
  for (int j = 0; j < 4; ++j) {
    float4 xv = xr[j];
    float4 av = a0[j];
    float4 bv = a1[j];
    s0 += xv.x * av.x + xv.y * av.y + xv.z * av.z + xv.w * av.w;
    s1 += xv.x * bv.x + xv.y * bv.y + xv.z * bv.z + xv.w * bv.w;
  }
#pragma unroll
  for (int m = 8; m >= 1; m >>= 1) {
    s0 += __shfl_xor(s0, m, 64);  // masks <16 stay within the 16-lane group
    s1 += __shfl_xor(s1, m, 64);
  }
  if (gl == 0) {
    s_src[node] = s0;
    s_dst[node] = s1;
  }
}

// Kernel B: fused exp + segment-sum, 3 partition passes per slice.
// Block (s,p): stream slice s's row (unpredicated int4); for rows in
// partition p only: load col (predicated scalar), gather s_src/s_dst
// (400 KB tables, L2-resident), leaky+exp in f32, LDS-atomic-accumulate.
// NO e store anymore (edge_div recomputes exp) -> accumulates UNROUNDED
// f32 exp; partial tile stored as bf16 (denom rel err <= 0.4%, absmax
// budget 1.55e-2, current margin 3.9e-3).
// Max-subtraction of softmax cancels algebraically -> no segment-max pass.
// Grid (FS_S, FS_P): linear id = s + 80p == s (mod 8) -> the 3 sibling
// blocks of a slice share an XCD and run concurrently -> passes 2,3 of the
// idx stream hit that XCD's L2.
__global__ __launch_bounds__(BLK) void fused_segsum_kernel(
    const int* __restrict__ row,
    const int* __restrict__ col,
    const float* __restrict__ s_src,
    const float* __restrict__ s_dst,
    unsigned short* __restrict__ partial /* [FS_S][NN] bf16 */) {
  __shared__ float acc[FS_PART];  // 160000 B
  int s  = blockIdx.x;
  int p  = blockIdx.y;
  int lo = p * FS_PART;
  for (int i = threadIdx.x; i < FS_PART; i += BLK) acc[i] = 0.0f;
  __syncthreads();
  const int4* row4 = (const int4*)(row + s * FS_ESL);
  const int*  cols = col + s * FS_ESL;
  const int n8 = FS_ESL / 8;  // 5000

#define FS_SLOT(r, j)                                      \
  do {                                                     \
    int rr = (r)-lo;                                       \
    if ((unsigned)rr < FS_PART) {                          \
      float a = s_src[(r)] + s_dst[cols[8 * i + (j)]];     \
      a = (a > 0.0f) ? a : NEG_SLOPE * a;                  \
      atomicAdd(&acc[rr], __expf(a));                      \
    }                                                      \
  } while (0)

  for (int i = threadIdx.x; i < n8; i += BLK) {
    int4 ra = row4[2 * i], rb = row4[2 * i + 1];
    FS_SLOT(ra.x, 0);
    FS_SLOT(ra.y, 1);
    FS_SLOT(ra.z, 2);
    FS_SLOT(ra.w, 3);
    FS_SLOT(rb.x, 4);
    FS_SLOT(rb.y, 5);
    FS_SLOT(rb.z, 6);
    FS_SLOT(rb.w, 7);
  }
#undef FS_SLOT
  __syncthreads();
  int cnt = NN - lo;
  if (cnt > FS_PART) cnt = FS_PART;
  unsigned short* outp = partial + (size_t)s * NN + lo;
  for (int i = threadIdx.x; i < cnt; i += BLK) outp[i] = f32_to_bf16(acc[i]);
}

// Kernel C: fold 80 bf16 slice-partials (ushort8 = 16 B loads), store
// reciprocal. 16 MB read + 0.4 MB write -> ~3 us.
__global__ __launch_bounds__(256) void reduce_kernel(
    const unsigned short* __restrict__ partial,
    float* __restrict__ denom) {
  int t = blockIdx.x * blockDim.x + threadIdx.x;  // 8 nodes per thread
  if (t >= NN / 8) return;
  float sum[8] = {0.f, 0.f, 0.f, 0.f, 0.f, 0.f, 0.f, 0.f};
#pragma unroll 8
  for (int s = 0; s < FS_S; ++s) {
    ushort8 v = ((const ushort8*)(partial + (size_t)s * NN))[t];
#pragma unroll
    for (int j = 0; j < 8; ++j) sum[j] += bf16_to_f32(v[j]);
  }
  float4 r0 = make_float4(1.f / sum[0], 1.f / sum[1], 1.f / sum[2], 1.f / sum[3]);
  float4 r1 = make_float4(1.f / sum[4], 1.f / sum[5], 1.f / sum[6], 1.f / sum[7]);
  ((float4*)denom)[2 * t]     = r0;
  ((float4*)denom)[2 * t + 1] = r1;
}

// Kernel D: 8 edges/thread. Recomputes exp from s_src/s_dst gathers (no
// e_buf), multiplies by denom reciprocal gather. All gather tables (s_src,
// s_dst, denom = 1.2 MB total) are L2-resident; 25.6M v_exp_f32 ~ 3 us VALU.
__global__ __launch_bounds__(256) void edge_div_kernel(
    const int4* __restrict__ row4,
    const int4* __restrict__ col4,
    const float* __restrict__ s_src,
    const float* __restrict__ s_dst,
    const float* __restrict__ denom,
    float4* __restrict__ out4) {
  int i = blockIdx.x * blockDim.x + threadIdx.x;
  if (i >= NE / 8) return;
  int4 ra = row4[2 * i], rb = row4[2 * i + 1];
  int4 ca = col4[2 * i], cb = col4[2 * i + 1];
  float a0 = s_src[ra.x] + s_dst[ca.x];
  float a1 = s_src[ra.y] + s_dst[ca.y];
  float a2 = s_src[ra.z] + s_dst[ca.z];
  float a3 = s_src[ra.w] + s_dst[ca.w];
  float a4 = s_src[rb.x] + s_dst[cb.x];
  float a5 = s_src[rb.y] + s_dst[cb.y];
  float a6 = s_src[rb.z] + s_dst[cb.z];
  float a7 = s_src[rb.w] + s_dst[cb.w];
  a0 = (a0 > 0.0f) ? a0 : NEG_SLOPE * a0;
  a1 = (a1 > 0.0f) ? a1 : NEG_SLOPE * a1;
  a2 = (a2 > 0.0f) ? a2 : NEG_SLOPE * a2;
  a3 = (a3 > 0.0f) ? a3 : NEG_SLOPE * a3;
  a4 = (a4 > 0.0f) ? a4 : NEG_SLOPE * a4;
  a5 = (a5 > 0.0f) ? a5 : NEG_SLOPE * a5;
  a6 = (a6 > 0.0f) ? a6 : NEG_SLOPE * a6;
  a7 = (a7 > 0.0f) ? a7 : NEG_SLOPE * a7;
  float4 oa, ob;
  oa.x = __expf(a0) * denom[ra.x];
  oa.y = __expf(a1) * denom[ra.y];
  oa.z = __expf(a2) * denom[ra.z];
  oa.w = __expf(a3) * denom[ra.w];
  ob.x = __expf(a4) * denom[rb.x];
  ob.y = __expf(a5) * denom[rb.y];
  ob.z = __expf(a6) * denom[rb.z];
  ob.w = __expf(a7) * denom[rb.w];
  out4[2 * i]     = oa;
  out4[2 * i + 1] = ob;
}

extern "C" void kernel_launch(void* const* d_in, const int* in_sizes, int n_in,
                              void* d_out, int out_size, void* d_ws, size_t ws_size,
                              hipStream_t stream) {
  const float* x   = (const float*)d_in[0];
  const float* att = (const float*)d_in[1];
  const int* ei    = (const int*)d_in[2];  // (2, E): row then col (int32)
  const int* row   = ei;
  const int* col   = ei + NE;
  const int4* row4 = (const int4*)ei;
  const int4* col4 = (const int4*)(ei + NE);
  float4* out4     = (float4*)d_out;  // E floats, final output

  float* s_src           = (float*)d_ws;              // N f32
  float* s_dst           = s_src + NN;                // N f32
  float* denom           = s_dst + NN;                // N f32
  unsigned short* partial = (unsigned short*)(denom + NN);  // FS_S*N bf16 (16 MB)

  node_scores_kernel<<<(NN * 16 + 255) / 256, 256, 0, stream>>>(x, att, s_src, s_dst);
  dim3 fs_grid(FS_S, FS_P);
  fused_segsum_kernel<<<fs_grid, BLK, 0, stream>>>(row, col, s_src, s_dst, partial);
  reduce_kernel<<<(NN / 8 + 255) / 256, 256, 0, stream>>>(partial, denom);
  edge_div_kernel<<<(NE / 8 + 255) / 256, 256, 0, stream>>>(
      row4, col4, s_src, s_dst, denom, out4);
}

// Round 7
// 224.715 us; speedup vs baseline: 1.5348x; 1.1242x over previous
//
#include <hip/hip_runtime.h>

#define NN 100000
#define NE 3200000
#define CC 256
#define NEG_SLOPE 0.2f

// Fused exp+segsum: 80 edge slices x 3 node-partition passes = 240 blocks
// (1 per CU; 160 KB LDS forces 1 block/CU anyway).
#define FS_S 80
#define FS_P 3
#define FS_PART 40000        // f32 acc = 160000 B LDS (<= 163840 limit)
#define FS_ESL (NE / FS_S)   // 40000 edges per slice
#define BLK 1024

typedef __attribute__((ext_vector_type(8))) _Float16 half8;
typedef __attribute__((ext_vector_type(8))) unsigned short ushort8;

// round-to-nearest f32 -> bf16 bits
__device__ __forceinline__ unsigned short f32_to_bf16(float f) {
  union { float f; unsigned int u; } v; v.f = f;
  unsigned int b = v.u + 0x7FFFu + ((v.u >> 16) & 1u);
  return (unsigned short)(b >> 16);
}
__device__ __forceinline__ float bf16_to_f32(unsigned short h) {
  union { unsigned int u; float f; } v; v.u = ((unsigned int)h) << 16;
  return v.f;
}

// Kernel A: dual dot product, 16 lanes per node (4 nodes/wave).
// Lane gl loads x[node][16gl .. 16gl+15] (4 consecutive float4 = 64 B/lane).
// Reads x (102.4 MB) once, fully coalesced -> ~17 us at HBM floor.
__global__ __launch_bounds__(256) void node_scores_kernel(
    const float* __restrict__ x,
    const float* __restrict__ att,
    float* __restrict__ s_src,
    float* __restrict__ s_dst) {
  int t    = blockIdx.x * blockDim.x + threadIdx.x;
  int node = t >> 4;
  int gl   = t & 15;
  if (node >= NN) return;
  const float4* xr = (const float4*)(x + (size_t)node * CC) + gl * 4;
  const float4* a0 = (const float4*)att + gl * 4;         // att[:C]
  const float4* a1 = (const float4*)(att + CC) + gl * 4;  // att[C:]
  float s0 = 0.f, s1 = 0.f;
#pragma unroll
  for (int j = 0; j < 4; ++j) {
    float4 xv = xr[j];
    float4 av = a0[j];
    float4 bv = a1[j];
    s0 += xv.x * av.x + xv.y * av.y + xv.z * av.z + xv.w * av.w;
    s1 += xv.x * bv.x + xv.y * bv.y + xv.z * bv.z + xv.w * bv.w;
  }
#pragma unroll
  for (int m = 8; m >= 1; m >>= 1) {
    s0 += __shfl_xor(s0, m, 64);  // masks <16 stay within the 16-lane group
    s1 += __shfl_xor(s1, m, 64);
  }
  if (gl == 0) {
    s_src[node] = s0;
    s_dst[node] = s1;
  }
}

// Kernel B: fused exp + segment-sum, 3 partition passes per slice.
// Block (s,p): stream slice s's row AND col (unpredicated int4 -> no
// per-slot exec-masked scalar loads); for rows in partition p only:
// gather s_src/s_dst (predicated; total gather volume across all passes
// = 2 x NE since each edge hits exactly one partition), leaky+exp,
// store e (f16, rounded), LDS-atomic-accumulate f32.
// Partial tile stored as bf16 (denom rel err <= 0.4%; round-6 measured
// absmax unchanged at 3.9e-3 with bf16 partials; budget 1.55e-2).
// Max-subtraction of softmax cancels algebraically -> no segment-max pass.
// exp(alpha) in [e^-2, e^8]: f16 rel err 5e-4.
// Grid (FS_S, FS_P): linear id = s + 80p == s (mod 8) -> the 3 sibling
// blocks of a slice share an XCD and run concurrently -> passes 2,3 of
// the idx stream hit that XCD's L2.
__global__ __launch_bounds__(BLK) void fused_segsum_kernel(
    const int* __restrict__ row,
    const int* __restrict__ col,
    const float* __restrict__ s_src,
    const float* __restrict__ s_dst,
    _Float16* __restrict__ e_out,
    unsigned short* __restrict__ partial /* [FS_S][NN] bf16 */) {
  __shared__ float acc[FS_PART];  // 160000 B
  int s  = blockIdx.x;
  int p  = blockIdx.y;
  int lo = p * FS_PART;
  for (int i = threadIdx.x; i < FS_PART; i += BLK) acc[i] = 0.0f;
  __syncthreads();
  const int4* row4 = (const int4*)(row + s * FS_ESL);
  const int4* col4 = (const int4*)(col + s * FS_ESL);
  _Float16* eo = e_out + (size_t)s * FS_ESL;
  const int n8 = FS_ESL / 8;  // 5000

#define FS_SLOT(r, c, j)                                   \
  do {                                                     \
    int rr = (r)-lo;                                       \
    if ((unsigned)rr < FS_PART) {                          \
      float a = s_src[(r)] + s_dst[(c)];                   \
      a = (a > 0.0f) ? a : NEG_SLOPE * a;                  \
      _Float16 h = (_Float16)__expf(a);                    \
      eo[8 * i + (j)] = h;                                 \
      atomicAdd(&acc[rr], (float)h);                       \
    }                                                      \
  } while (0)

  for (int i = threadIdx.x; i < n8; i += BLK) {
    int4 ra = row4[2 * i], rb = row4[2 * i + 1];
    int4 ca = col4[2 * i], cb = col4[2 * i + 1];
    FS_SLOT(ra.x, ca.x, 0);
    FS_SLOT(ra.y, ca.y, 1);
    FS_SLOT(ra.z, ca.z, 2);
    FS_SLOT(ra.w, ca.w, 3);
    FS_SLOT(rb.x, cb.x, 4);
    FS_SLOT(rb.y, cb.y, 5);
    FS_SLOT(rb.z, cb.z, 6);
    FS_SLOT(rb.w, cb.w, 7);
  }
#undef FS_SLOT
  __syncthreads();
  int cnt = NN - lo;
  if (cnt > FS_PART) cnt = FS_PART;
  unsigned short* outp = partial + (size_t)s * NN + lo;
  for (int i = threadIdx.x; i < cnt; i += BLK) outp[i] = f32_to_bf16(acc[i]);
}

// Kernel C: fold 80 bf16 slice-partials (ushort8 = 16 B loads), store
// reciprocal. 16 MB read + 0.4 MB write -> ~3 us.
__global__ __launch_bounds__(256) void reduce_kernel(
    const unsigned short* __restrict__ partial,
    float* __restrict__ denom) {
  int t = blockIdx.x * blockDim.x + threadIdx.x;  // 8 nodes per thread
  if (t >= NN / 8) return;
  float sum[8] = {0.f, 0.f, 0.f, 0.f, 0.f, 0.f, 0.f, 0.f};
#pragma unroll 8
  for (int s = 0; s < FS_S; ++s) {
    ushort8 v = ((const ushort8*)(partial + (size_t)s * NN))[t];
#pragma unroll
    for (int j = 0; j < 8; ++j) sum[j] += bf16_to_f32(v[j]);
  }
  float4 r0 = make_float4(1.f / sum[0], 1.f / sum[1], 1.f / sum[2], 1.f / sum[3]);
  float4 r1 = make_float4(1.f / sum[4], 1.f / sum[5], 1.f / sum[6], 1.f / sum[7]);
  ((float4*)denom)[2 * t]     = r0;
  ((float4*)denom)[2 * t + 1] = r1;
}

// Kernel D: 8 edges/thread, normalize e (fp16 stream) into final fp32 out.
// ONE random gather pass (denom[row], 400 KB L2-resident table) — the
// recompute-from-scores variant (3 gather passes) measured +26 us in r6.
__global__ __launch_bounds__(256) void edge_div_kernel(
    const int4* __restrict__ row4,
    const half8* __restrict__ e,
    const float* __restrict__ denom,
    float4* __restrict__ out4) {
  int i = blockIdx.x * blockDim.x + threadIdx.x;
  if (i >= NE / 8) return;
  int4 ra = row4[2 * i], rb = row4[2 * i + 1];
  half8 ev = e[i];
  float4 oa, ob;
  oa.x = (float)ev[0] * denom[ra.x];
  oa.y = (float)ev[1] * denom[ra.y];
  oa.z = (float)ev[2] * denom[ra.z];
  oa.w = (float)ev[3] * denom[ra.w];
  ob.x = (float)ev[4] * denom[rb.x];
  ob.y = (float)ev[5] * denom[rb.y];
  ob.z = (float)ev[6] * denom[rb.z];
  ob.w = (float)ev[7] * denom[rb.w];
  out4[2 * i]     = oa;
  out4[2 * i + 1] = ob;
}

extern "C" void kernel_launch(void* const* d_in, const int* in_sizes, int n_in,
                              void* d_out, int out_size, void* d_ws, size_t ws_size,
                              hipStream_t stream) {
  const float* x   = (const float*)d_in[0];
  const float* att = (const float*)d_in[1];
  const int* ei    = (const int*)d_in[2];  // (2, E): row then col (int32)
  const int* row   = ei;
  const int* col   = ei + NE;
  const int4* row4 = (const int4*)ei;
  float4* out4     = (float4*)d_out;  // E floats, final output

  float* s_src    = (float*)d_ws;            // N f32
  float* s_dst    = s_src + NN;              // N f32
  float* denom    = s_dst + NN;              // N f32
  _Float16* e_buf = (_Float16*)(denom + NN); // E f16 (6.4 MB)
  unsigned short* partial = (unsigned short*)(e_buf + NE);  // FS_S*N bf16 (16 MB)

  node_scores_kernel<<<(NN * 16 + 255) / 256, 256, 0, stream>>>(x, att, s_src, s_dst);
  dim3 fs_grid(FS_S, FS_P);
  fused_segsum_kernel<<<fs_grid, BLK, 0, stream>>>(
      row, col, s_src, s_dst, e_buf, partial);
  reduce_kernel<<<(NN / 8 + 255) / 256, 256, 0, stream>>>(partial, denom);
  edge_div_kernel<<<(NE / 8 + 255) / 256, 256, 0, stream>>>(
      row4, (const half8*)e_buf, denom, out4);
}